// Round 1
// baseline (1115.716 us; speedup 1.0000x reference)
//
#include <hip/hip_runtime.h>

#define EPS_C   0.01f
#define NU      128
#define DIN     64
#define CHUNK   64
#define COUT    10

// One workgroup per batch element; whole T-loop in-kernel.
// Thread (u = tid&127, half = tid>>7) owns:
//   Areg[j] = A[voff+j][u],  Wreg[j] = W[voff+j][u]   (64 each, fp32, in VGPRs)
//   Ereg[i] = E_w[u][ioff+i]                          (32, in VGPRs)
// h (128 fp32) lives in LDS; per step each half computes a 64-long partial dot,
// partials combined through LDS. x staged in 64-timestep LDS chunks.
__global__ __launch_bounds__(256, 2)
void noisy_rnn(const float* __restrict__ x,
               const float* __restrict__ E_w,
               const float* __restrict__ E_b,
               const float* __restrict__ B_p,
               const float* __restrict__ C_p,
               const float* __restrict__ D_w,
               const float* __restrict__ D_b,
               float* __restrict__ out,
               int T)
{
    const int b    = blockIdx.x;
    const int tid  = threadIdx.x;
    const int u    = tid & (NU - 1);
    const int half = tid >> 7;       // 0 or 1
    const int voff = half << 6;      // v-range start: 0 or 64
    const int ioff = half << 5;      // z i-range start: 0 or 32

    __shared__ float h[NU];
    __shared__ float sA[2][NU];
    __shared__ float sW[2][NU];
    __shared__ float xs[CHUNK * DIN];   // 16 KB staging of x[b][t0:t0+64][:]

    float Areg[64], Wreg[64], Ereg[32];

    // A = B_p - 0.6*B_p^T - 0.01*I ; thread needs column u, rows voff..voff+63.
    // Column part B_p[v][u]: coalesced across lanes. Row part B_p[u][v]: float4
    // per thread (one-time, L2/L3 resident).
    #pragma unroll
    for (int j = 0; j < 64; j += 4) {
        const int v0 = voff + j;
        float4 r = *(const float4*)&B_p[u * NU + v0];
        Areg[j+0] = B_p[(v0+0)*NU + u] - 0.6f * r.x - ((v0+0) == u ? 0.01f : 0.0f);
        Areg[j+1] = B_p[(v0+1)*NU + u] - 0.6f * r.y - ((v0+1) == u ? 0.01f : 0.0f);
        Areg[j+2] = B_p[(v0+2)*NU + u] - 0.6f * r.z - ((v0+2) == u ? 0.01f : 0.0f);
        Areg[j+3] = B_p[(v0+3)*NU + u] - 0.6f * r.w - ((v0+3) == u ? 0.01f : 0.0f);
    }
    #pragma unroll
    for (int j = 0; j < 64; j += 4) {
        const int v0 = voff + j;
        float4 r = *(const float4*)&C_p[u * NU + v0];
        Wreg[j+0] = C_p[(v0+0)*NU + u] - 0.6f * r.x - ((v0+0) == u ? 0.01f : 0.0f);
        Wreg[j+1] = C_p[(v0+1)*NU + u] - 0.6f * r.y - ((v0+1) == u ? 0.01f : 0.0f);
        Wreg[j+2] = C_p[(v0+2)*NU + u] - 0.6f * r.z - ((v0+2) == u ? 0.01f : 0.0f);
        Wreg[j+3] = C_p[(v0+3)*NU + u] - 0.6f * r.w - ((v0+3) == u ? 0.01f : 0.0f);
    }
    #pragma unroll
    for (int i = 0; i < 32; i += 4) {
        float4 e = *(const float4*)&E_w[u * DIN + ioff + i];
        Ereg[i+0] = e.x; Ereg[i+1] = e.y; Ereg[i+2] = e.z; Ereg[i+3] = e.w;
    }
    const float eb = E_b[u];

    if (tid < NU) h[tid] = 0.0f;

    for (int t0 = 0; t0 < T; t0 += CHUNK) {
        __syncthreads();   // protect xs from prior chunk's readers; also covers h init
        {
            const float4* src = (const float4*)(x + ((size_t)b * T + t0) * DIN);
            float4* dst = (float4*)xs;
            #pragma unroll
            for (int k = 0; k < (CHUNK * DIN / 4) / 256; ++k)
                dst[tid + k * 256] = src[tid + k * 256];
        }
        __syncthreads();

        for (int tl = 0; tl < CHUNK; ++tl) {
            float accA = 0.0f, accW = 0.0f;
            #pragma unroll
            for (int j = 0; j < 64; j += 4) {
                float4 hh = *(const float4*)&h[voff + j];   // broadcast read
                accA = fmaf(hh.x, Areg[j+0], accA);
                accA = fmaf(hh.y, Areg[j+1], accA);
                accA = fmaf(hh.z, Areg[j+2], accA);
                accA = fmaf(hh.w, Areg[j+3], accA);
                accW = fmaf(hh.x, Wreg[j+0], accW);
                accW = fmaf(hh.y, Wreg[j+1], accW);
                accW = fmaf(hh.z, Wreg[j+2], accW);
                accW = fmaf(hh.w, Wreg[j+3], accW);
            }
            float accZ = 0.0f;
            #pragma unroll
            for (int i = 0; i < 32; i += 4) {
                float4 xx = *(const float4*)&xs[tl * DIN + ioff + i];  // broadcast
                accZ = fmaf(xx.x, Ereg[i+0], accZ);
                accZ = fmaf(xx.y, Ereg[i+1], accZ);
                accZ = fmaf(xx.z, Ereg[i+2], accZ);
                accZ = fmaf(xx.w, Ereg[i+3], accZ);
            }
            sA[half][u] = accA;
            sW[half][u] = accW + accZ;
            __syncthreads();
            if (half == 0) {
                float yA  = sA[0][u] + sA[1][u];
                float arg = sW[0][u] + sW[1][u] + eb;
                // tanh(arg) = 1 - 2/(exp(2*arg)+1)  (inf-safe both tails)
                float e2  = __expf(2.0f * arg);
                float th  = 1.0f - 2.0f / (e2 + 1.0f);
                h[u] += EPS_C * (yA + th);
            }
            __syncthreads();
        }
    }

    // out[b][c] = h_final . D_w[c][:] + D_b[c]
    if (tid < COUT) {
        float acc = D_b[tid];
        #pragma unroll 8
        for (int uu = 0; uu < NU; ++uu)
            acc = fmaf(h[uu], D_w[tid * NU + uu], acc);
        out[b * COUT + tid] = acc;
    }
}

extern "C" void kernel_launch(void* const* d_in, const int* in_sizes, int n_in,
                              void* d_out, int out_size, void* d_ws, size_t ws_size,
                              hipStream_t stream)
{
    const float* x   = (const float*)d_in[0];
    const float* E_w = (const float*)d_in[1];
    const float* E_b = (const float*)d_in[2];
    const float* B_p = (const float*)d_in[3];
    const float* C_p = (const float*)d_in[4];
    const float* D_w = (const float*)d_in[5];
    const float* D_b = (const float*)d_in[6];
    float* out = (float*)d_out;

    const int B = out_size / COUT;            // 512
    const int T = in_sizes[0] / (B * DIN);    // 1024

    noisy_rnn<<<B, 256, 0, stream>>>(x, E_w, E_b, B_p, C_p, D_w, D_b, out, T);
}

// Round 2
// 961.640 us; speedup vs baseline: 1.1602x; 1.1602x over previous
//
#include <hip/hip_runtime.h>

#define EPS_C   0.01f
#define NU      128
#define DIN     64
#define CHUNK   64
#define COUT    10
#define NT      512

// One workgroup (512 threads) per batch element; whole T-loop in-kernel.
// Thread (u = tid&127, q = tid>>7) owns a QUARTER of the dot products:
//   Areg[j] = A[32q+j][u],  Wreg[j] = W[32q+j][u]   (32 each, fp32, VGPRs)
//   Ereg[i] = E_w[u][16q+i]                          (16, VGPRs)
// Total 80 array floats/thread -> fits 128-VGPR budget (4 waves/SIMD), no spill.
// h (128 fp32) in LDS; 4 partial sums per unit combined through LDS.
__global__ __launch_bounds__(NT, 4)
void noisy_rnn(const float* __restrict__ x,
               const float* __restrict__ E_w,
               const float* __restrict__ E_b,
               const float* __restrict__ B_p,
               const float* __restrict__ C_p,
               const float* __restrict__ D_w,
               const float* __restrict__ D_b,
               float* __restrict__ out,
               int T)
{
    const int b    = blockIdx.x;
    const int tid  = threadIdx.x;
    const int u    = tid & (NU - 1);
    const int q    = tid >> 7;       // 0..3
    const int voff = q << 5;         // h-rows this thread covers: 32q..32q+31
    const int ioff = q << 4;         // x-cols this thread covers: 16q..16q+15

    __shared__ float h[NU];
    __shared__ float sA[4][NU];
    __shared__ float sW[4][NU];
    __shared__ float xs[CHUNK * DIN];   // 16 KB: x[b][t0:t0+64][:]

    float Areg[32], Wreg[32], Ereg[16];

    // A = B_p - 0.6*B_p^T - 0.01*I ; thread needs rows voff..voff+31 of column u.
    #pragma unroll
    for (int j = 0; j < 32; j += 4) {
        const int v0 = voff + j;
        float4 r = *(const float4*)&B_p[u * NU + v0];
        Areg[j+0] = B_p[(v0+0)*NU + u] - 0.6f * r.x - ((v0+0) == u ? 0.01f : 0.0f);
        Areg[j+1] = B_p[(v0+1)*NU + u] - 0.6f * r.y - ((v0+1) == u ? 0.01f : 0.0f);
        Areg[j+2] = B_p[(v0+2)*NU + u] - 0.6f * r.z - ((v0+2) == u ? 0.01f : 0.0f);
        Areg[j+3] = B_p[(v0+3)*NU + u] - 0.6f * r.w - ((v0+3) == u ? 0.01f : 0.0f);
    }
    #pragma unroll
    for (int j = 0; j < 32; j += 4) {
        const int v0 = voff + j;
        float4 r = *(const float4*)&C_p[u * NU + v0];
        Wreg[j+0] = C_p[(v0+0)*NU + u] - 0.6f * r.x - ((v0+0) == u ? 0.01f : 0.0f);
        Wreg[j+1] = C_p[(v0+1)*NU + u] - 0.6f * r.y - ((v0+1) == u ? 0.01f : 0.0f);
        Wreg[j+2] = C_p[(v0+2)*NU + u] - 0.6f * r.z - ((v0+2) == u ? 0.01f : 0.0f);
        Wreg[j+3] = C_p[(v0+3)*NU + u] - 0.6f * r.w - ((v0+3) == u ? 0.01f : 0.0f);
    }
    #pragma unroll
    for (int i = 0; i < 16; i += 4) {
        float4 e = *(const float4*)&E_w[u * DIN + ioff + i];
        Ereg[i+0] = e.x; Ereg[i+1] = e.y; Ereg[i+2] = e.z; Ereg[i+3] = e.w;
    }
    const float eb = (tid < NU) ? E_b[tid] : 0.0f;

    if (tid < NU) h[tid] = 0.0f;

    for (int t0 = 0; t0 < T; t0 += CHUNK) {
        __syncthreads();   // h init on first entry / prior-chunk quiesce
        {
            const float4* src = (const float4*)(x + ((size_t)b * T + t0) * DIN);
            float4* dst = (float4*)xs;
            #pragma unroll
            for (int k = 0; k < (CHUNK * DIN / 4) / NT; ++k)
                dst[tid + k * NT] = src[tid + k * NT];
        }
        __syncthreads();

        for (int tl = 0; tl < CHUNK; ++tl) {
            float accA = 0.0f, accW = 0.0f;
            #pragma unroll
            for (int j = 0; j < 32; j += 4) {
                float4 hh = *(const float4*)&h[voff + j];   // broadcast read
                accA = fmaf(hh.x, Areg[j+0], accA);
                accA = fmaf(hh.y, Areg[j+1], accA);
                accA = fmaf(hh.z, Areg[j+2], accA);
                accA = fmaf(hh.w, Areg[j+3], accA);
                accW = fmaf(hh.x, Wreg[j+0], accW);
                accW = fmaf(hh.y, Wreg[j+1], accW);
                accW = fmaf(hh.z, Wreg[j+2], accW);
                accW = fmaf(hh.w, Wreg[j+3], accW);
            }
            float accZ = 0.0f;
            #pragma unroll
            for (int i = 0; i < 16; i += 4) {
                float4 xx = *(const float4*)&xs[tl * DIN + ioff + i];  // broadcast
                accZ = fmaf(xx.x, Ereg[i+0], accZ);
                accZ = fmaf(xx.y, Ereg[i+1], accZ);
                accZ = fmaf(xx.z, Ereg[i+2], accZ);
                accZ = fmaf(xx.w, Ereg[i+3], accZ);
            }
            sA[q][u] = accA;
            sW[q][u] = accW + accZ;
            __syncthreads();
            if (tid < NU) {
                float yA  = sA[0][tid] + sA[1][tid] + sA[2][tid] + sA[3][tid];
                float arg = sW[0][tid] + sW[1][tid] + sW[2][tid] + sW[3][tid] + eb;
                // tanh(arg) = 1 - 2/(exp(2*arg)+1)  (inf-safe both tails)
                float e2  = __expf(2.0f * arg);
                float th  = 1.0f - 2.0f / (e2 + 1.0f);
                h[tid] += EPS_C * (yA + th);
            }
            __syncthreads();
        }
    }

    // out[b][c] = h_final . D_w[c][:] + D_b[c]
    if (tid < COUT) {
        float acc = D_b[tid];
        #pragma unroll 8
        for (int uu = 0; uu < NU; ++uu)
            acc = fmaf(h[uu], D_w[tid * NU + uu], acc);
        out[b * COUT + tid] = acc;
    }
}

extern "C" void kernel_launch(void* const* d_in, const int* in_sizes, int n_in,
                              void* d_out, int out_size, void* d_ws, size_t ws_size,
                              hipStream_t stream)
{
    const float* x   = (const float*)d_in[0];
    const float* E_w = (const float*)d_in[1];
    const float* E_b = (const float*)d_in[2];
    const float* B_p = (const float*)d_in[3];
    const float* C_p = (const float*)d_in[4];
    const float* D_w = (const float*)d_in[5];
    const float* D_b = (const float*)d_in[6];
    float* out = (float*)d_out;

    const int B = out_size / COUT;            // 512
    const int T = in_sizes[0] / (B * DIN);    // 1024

    noisy_rnn<<<B, NT, 0, stream>>>(x, E_w, E_b, B_p, C_p, D_w, D_b, out, T);
}

// Round 3
// 614.014 us; speedup vs baseline: 1.8171x; 1.5662x over previous
//
#include <hip/hip_runtime.h>

#define EPS_C  0.01f
#define NU     128
#define DIN    64
#define COUT   10
#define TC     64      // timesteps staged per LDS chunk

typedef float     f32x4 __attribute__((ext_vector_type(4)));
typedef _Float16  f16x8 __attribute__((ext_vector_type(8)));
typedef _Float16  f16x4 __attribute__((ext_vector_type(4)));

// One block per 2 batch rows (grid=256, ~1 block/CU). 256 threads = 4 waves.
// Per step: [h@A | h@W + x@E] via mfma_f32_16x16x32_f16; M-dim = 2 batch rows
// (rows 2-15 of the tile are garbage and never read). Wave `wid` owns n-tiles
// {2*wid, 2*wid+1} of both A and W as B-operand register fragments:
//   B-frag lane L elem j  <->  Mat[k = (L>>4)*8 + j][n = 16*tile + (L&15)]
// A-operand (H,X) frag: lane L elem j <-> H[m = L&15][k = (L>>4)*8 + j];
// only m in {0,1} is real -> other lanes read a broadcast LDS address.
// C/D frag: col = lane&15, row = (lane>>4)*4 + reg  -> rows 0,1 live in
// lanes 0..15 regs 0,1. Master h is fp32 in LDS; f16 copy feeds the MFMAs.
__global__ __launch_bounds__(256, 2)
void noisy_rnn_mfma(const float* __restrict__ x,
                    const float* __restrict__ E_w,
                    const float* __restrict__ E_b,
                    const float* __restrict__ B_p,
                    const float* __restrict__ C_p,
                    const float* __restrict__ D_w,
                    const float* __restrict__ D_b,
                    float* __restrict__ out,
                    int T)
{
    const int tid  = threadIdx.x;
    const int lane = tid & 63;
    const int wid  = tid >> 6;       // wave 0..3
    const int lid  = lane & 15;
    const int quad = lane >> 4;
    const int g0   = blockIdx.x * 2; // batch rows g0, g0+1

    __shared__ _Float16 xs16[2 * TC * DIN];   // 16 KB staged x (f16)
    __shared__ _Float16 h16[2][NU];           // f16 copy of h for MFMA
    __shared__ float    hf[2][NU];            // fp32 master h
    __shared__ float    sY[2][NU];            // h@A result rows
    __shared__ float    sArg[2][NU];          // h@W + z + E_b rows

    // ---- Build weight B-operand fragments (one-time, L2/L3-cached) ----
    f16x8 Af[2][4], Wf[2][4], Ef[2][2];
    float ebv[2];
    #pragma unroll
    for (int t = 0; t < 2; ++t) {
        const int n = (wid * 2 + t) * 16 + lid;
        #pragma unroll
        for (int c = 0; c < 4; ++c) {
            f16x8 fa, fw;
            #pragma unroll
            for (int j = 0; j < 8; ++j) {
                const int k = c * 32 + quad * 8 + j;
                const float dg = (k == n) ? 0.01f : 0.0f;
                fa[j] = (_Float16)(B_p[k * NU + n] - 0.6f * B_p[n * NU + k] - dg);
                fw[j] = (_Float16)(C_p[k * NU + n] - 0.6f * C_p[n * NU + k] - dg);
            }
            Af[t][c] = fa;
            Wf[t][c] = fw;
        }
        #pragma unroll
        for (int c = 0; c < 2; ++c) {
            f16x8 fe;
            #pragma unroll
            for (int j = 0; j < 8; ++j) {
                const int k = c * 32 + quad * 8 + j;
                fe[j] = (_Float16)E_w[n * DIN + k];
            }
            Ef[t][c] = fe;
        }
        ebv[t] = E_b[n];
    }

    // ---- init h ----
    {
        const int r = tid >> 7, cc = tid & 127;
        hf[r][cc]  = 0.0f;
        h16[r][cc] = (_Float16)0.0f;
    }

    // H-fragment load pointers (loop-invariant): broadcast addr for m>=2 lanes
    const f16x8* hp0 = (lid < 2) ? (const f16x8*)&h16[lid][0 * 32 + quad * 8]
                                 : (const f16x8*)&h16[0][0];
    const f16x8* hp1 = (lid < 2) ? (const f16x8*)&h16[lid][1 * 32 + quad * 8]
                                 : (const f16x8*)&h16[0][0];
    const f16x8* hp2 = (lid < 2) ? (const f16x8*)&h16[lid][2 * 32 + quad * 8]
                                 : (const f16x8*)&h16[0][0];
    const f16x8* hp3 = (lid < 2) ? (const f16x8*)&h16[lid][3 * 32 + quad * 8]
                                 : (const f16x8*)&h16[0][0];
    const int xoffA = (lid < 2) ? (lid * (TC * DIN) + 0 * 32 + quad * 8) : 0;
    const int xoffB = (lid < 2) ? (lid * (TC * DIN) + 1 * 32 + quad * 8) : 0;

    for (int t0 = 0; t0 < T; t0 += TC) {
        __syncthreads();   // xs reuse quiesce; also covers h init on first pass
        {   // stage x[g0..g0+1][t0..t0+TC) -> f16 LDS
            const float4* s0 = (const float4*)(x + ((size_t)g0 * T + t0) * DIN);
            const float4* s1 = (const float4*)(x + ((size_t)(g0 + 1) * T + t0) * DIN);
            #pragma unroll
            for (int kk = 0; kk < (2 * TC * DIN / 4) / 256; ++kk) {
                const int f  = tid + kk * 256;
                const int bh = f >> 10;          // which batch row
                const int ix = f & 1023;         // float4 index within row-chunk
                float4 v = (bh ? s1 : s0)[ix];
                f16x4 h4;
                h4[0] = (_Float16)v.x; h4[1] = (_Float16)v.y;
                h4[2] = (_Float16)v.z; h4[3] = (_Float16)v.w;
                *(f16x4*)&xs16[f * 4] = h4;
            }
        }
        __syncthreads();

        for (int tl = 0; tl < TC; ++tl) {
            // A-operand fragments
            f16x8 h0 = *hp0, h1 = *hp1, h2 = *hp2, h3 = *hp3;
            f16x8 x0 = *(const f16x8*)&xs16[xoffA + tl * DIN];
            f16x8 x1 = *(const f16x8*)&xs16[xoffB + tl * DIN];

            f32x4 a0 = {0.f, 0.f, 0.f, 0.f};
            f32x4 a1 = {0.f, 0.f, 0.f, 0.f};
            f32x4 w0 = {ebv[0], ebv[0], ebv[0], ebv[0]};
            f32x4 w1 = {ebv[1], ebv[1], ebv[1], ebv[1]};

            a0 = __builtin_amdgcn_mfma_f32_16x16x32_f16(h0, Af[0][0], a0, 0, 0, 0);
            a1 = __builtin_amdgcn_mfma_f32_16x16x32_f16(h0, Af[1][0], a1, 0, 0, 0);
            w0 = __builtin_amdgcn_mfma_f32_16x16x32_f16(h0, Wf[0][0], w0, 0, 0, 0);
            w1 = __builtin_amdgcn_mfma_f32_16x16x32_f16(h0, Wf[1][0], w1, 0, 0, 0);
            a0 = __builtin_amdgcn_mfma_f32_16x16x32_f16(h1, Af[0][1], a0, 0, 0, 0);
            a1 = __builtin_amdgcn_mfma_f32_16x16x32_f16(h1, Af[1][1], a1, 0, 0, 0);
            w0 = __builtin_amdgcn_mfma_f32_16x16x32_f16(h1, Wf[0][1], w0, 0, 0, 0);
            w1 = __builtin_amdgcn_mfma_f32_16x16x32_f16(h1, Wf[1][1], w1, 0, 0, 0);
            a0 = __builtin_amdgcn_mfma_f32_16x16x32_f16(h2, Af[0][2], a0, 0, 0, 0);
            a1 = __builtin_amdgcn_mfma_f32_16x16x32_f16(h2, Af[1][2], a1, 0, 0, 0);
            w0 = __builtin_amdgcn_mfma_f32_16x16x32_f16(h2, Wf[0][2], w0, 0, 0, 0);
            w1 = __builtin_amdgcn_mfma_f32_16x16x32_f16(h2, Wf[1][2], w1, 0, 0, 0);
            a0 = __builtin_amdgcn_mfma_f32_16x16x32_f16(h3, Af[0][3], a0, 0, 0, 0);
            a1 = __builtin_amdgcn_mfma_f32_16x16x32_f16(h3, Af[1][3], a1, 0, 0, 0);
            w0 = __builtin_amdgcn_mfma_f32_16x16x32_f16(h3, Wf[0][3], w0, 0, 0, 0);
            w1 = __builtin_amdgcn_mfma_f32_16x16x32_f16(h3, Wf[1][3], w1, 0, 0, 0);
            w0 = __builtin_amdgcn_mfma_f32_16x16x32_f16(x0, Ef[0][0], w0, 0, 0, 0);
            w1 = __builtin_amdgcn_mfma_f32_16x16x32_f16(x0, Ef[1][0], w1, 0, 0, 0);
            w0 = __builtin_amdgcn_mfma_f32_16x16x32_f16(x1, Ef[0][1], w0, 0, 0, 0);
            w1 = __builtin_amdgcn_mfma_f32_16x16x32_f16(x1, Ef[1][1], w1, 0, 0, 0);

            // rows 0,1 of each D tile live in lanes 0..15, regs 0,1
            if (lane < 16) {
                const int n0 = (wid * 2) * 16 + lid;
                const int n1 = n0 + 16;
                sY[0][n0]   = a0[0];  sY[1][n0]   = a0[1];
                sY[0][n1]   = a1[0];  sY[1][n1]   = a1[1];
                sArg[0][n0] = w0[0];  sArg[1][n0] = w0[1];
                sArg[0][n1] = w1[0];  sArg[1][n1] = w1[1];
            }
            __syncthreads();

            {   // h update: 256 threads, one (row,col) each
                const int r = tid >> 7, cc = tid & 127;
                const float arg = sArg[r][cc];
                const float e2  = __expf(2.0f * arg);
                const float th  = 1.0f - 2.0f / (e2 + 1.0f);   // tanh, inf-safe
                const float hv  = hf[r][cc] + EPS_C * (sY[r][cc] + th);
                hf[r][cc]  = hv;
                h16[r][cc] = (_Float16)hv;
            }
            __syncthreads();
        }
    }

    // out[b][c] = h_final . D_w[c][:] + D_b[c]
    if (tid < 2 * COUT) {
        const int r = tid / COUT;
        const int c = tid - r * COUT;
        float acc = D_b[c];
        #pragma unroll 8
        for (int u = 0; u < NU; ++u)
            acc = fmaf(hf[r][u], D_w[c * NU + u], acc);
        out[(size_t)(g0 + r) * COUT + c] = acc;
    }
}

extern "C" void kernel_launch(void* const* d_in, const int* in_sizes, int n_in,
                              void* d_out, int out_size, void* d_ws, size_t ws_size,
                              hipStream_t stream)
{
    const float* x   = (const float*)d_in[0];
    const float* E_w = (const float*)d_in[1];
    const float* E_b = (const float*)d_in[2];
    const float* B_p = (const float*)d_in[3];
    const float* C_p = (const float*)d_in[4];
    const float* D_w = (const float*)d_in[5];
    const float* D_b = (const float*)d_in[6];
    float* out = (float*)d_out;

    const int B = out_size / COUT;            // 512
    const int T = in_sizes[0] / (B * DIN);    // 1024

    noisy_rnn_mfma<<<B / 2, 256, 0, stream>>>(x, E_w, E_b, B_p, C_p, D_w, D_b, out, T);
}